// Round 1
// baseline (409.724 us; speedup 1.0000x reference)
//
#include <hip/hip_runtime.h>

#define B_ 64
#define L_ 196
#define D_ 2048
#define I_ 512
#define M_ (B_*L_)   // 12544

typedef __attribute__((ext_vector_type(8))) short bf16x8;
typedef __attribute__((ext_vector_type(4))) float f32x4;

__device__ __forceinline__ unsigned short f2bf(float x){
  unsigned u = __float_as_uint(x);
  u += 0x7fffu + ((u >> 16) & 1u);
  return (unsigned short)(u >> 16);
}

// fp32 -> bf16, n4 = count/4
__global__ void cvt_bf16_kernel(const float* __restrict__ in, unsigned short* __restrict__ out, int n4){
  int i = blockIdx.x*blockDim.x + threadIdx.x;
  int stride = gridDim.x*blockDim.x;
  for (; i < n4; i += stride){
    float4 v = ((const float4*)in)[i];
    ushort4 o;
    o.x = f2bf(v.x); o.y = f2bf(v.y); o.z = f2bf(v.z); o.w = f2bf(v.w);
    ((ushort4*)out)[i] = o;
  }
}

// in: [R,C] fp32 row-major  ->  out: [C,R] bf16 row-major
__global__ void transpose_cvt_kernel(const float* __restrict__ in, unsigned short* __restrict__ out, int R, int C){
  __shared__ float tile[32][33];
  int c0 = blockIdx.x*32, r0 = blockIdx.y*32;
  int tx = threadIdx.x, ty = threadIdx.y; // blockDim (32,8)
  for (int i=0;i<32;i+=8)
    tile[ty+i][tx] = in[(size_t)(r0+ty+i)*C + c0 + tx];
  __syncthreads();
  for (int i=0;i<32;i+=8)
    out[(size_t)(c0+ty+i)*R + r0 + tx] = f2bf(tile[tx][ty+i]);
}

// hs[b][n] = b_h[n] + sum_k hidden[b][k] * W_h[k][n]
__global__ void hs_kernel(const float* __restrict__ hidden, const float* __restrict__ Wh,
                          const float* __restrict__ bh, float* __restrict__ hs){
  int n = blockIdx.x*blockDim.x + threadIdx.x; // 0..I_-1
  int b = blockIdx.y;
  const float* hrow = hidden + b*I_;
  float acc = bh[n];
  for (int k=0;k<I_;++k)
    acc = fmaf(hrow[k], Wh[(size_t)k*I_ + n], acc);
  hs[b*I_ + n] = acc;
}

// C[M,N] = A[M,K](bf16) x Bt[N,K](bf16)^T, 64x64 block tile, 4 waves (2x2), each wave 32x32.
// mode 0: out_bf16 = bf16(acc + bias[n] + hs[m/L_][n])   (t for GEMM2)
// mode 1: out_f32  = acc + bias[n]                        (e, written into d_out alpha region)
__launch_bounds__(256)
__global__ void gemm_kernel(const unsigned short* __restrict__ A,
                            const unsigned short* __restrict__ Bt,
                            int K, int N, int mode,
                            const float* __restrict__ bias,
                            const float* __restrict__ hs,
                            unsigned short* __restrict__ outb,
                            float* __restrict__ outf)
{
  __shared__ __align__(16) unsigned short Als[64][40]; // +8 pad breaks pow2 stride
  __shared__ __align__(16) unsigned short Bls[64][40];

  int tid = threadIdx.x;
  int m0 = blockIdx.y*64;
  int n0 = blockIdx.x*64;

  int lane = tid & 63;
  int wave = tid >> 6;
  int wm = (wave & 1)*32;
  int wn = (wave >> 1)*32;
  int q  = lane >> 4;
  int mr = lane & 15;

  int srow = tid >> 2;        // 0..63
  int scol = (tid & 3)*8;     // 0,8,16,24

  f32x4 acc[2][2];
  for (int i=0;i<2;i++) for (int j=0;j<2;j++) acc[i][j] = (f32x4){0.f,0.f,0.f,0.f};

  const unsigned short* Aptr = A  + (size_t)(m0 + srow)*K + scol;
  const unsigned short* Bptr = Bt + (size_t)(n0 + srow)*K + scol;

  for (int k0 = 0; k0 < K; k0 += 32){
    bf16x8 av = *(const bf16x8*)(Aptr + k0);
    bf16x8 bv = *(const bf16x8*)(Bptr + k0);
    __syncthreads();                       // previous iter's frag reads done
    *(bf16x8*)&Als[srow][scol] = av;
    *(bf16x8*)&Bls[srow][scol] = bv;
    __syncthreads();
    bf16x8 af0 = *(const bf16x8*)&Als[wm      + mr][q*8];
    bf16x8 af1 = *(const bf16x8*)&Als[wm + 16 + mr][q*8];
    bf16x8 bg0 = *(const bf16x8*)&Bls[wn      + mr][q*8];
    bf16x8 bg1 = *(const bf16x8*)&Bls[wn + 16 + mr][q*8];
    acc[0][0] = __builtin_amdgcn_mfma_f32_16x16x32_bf16(af0, bg0, acc[0][0], 0,0,0);
    acc[0][1] = __builtin_amdgcn_mfma_f32_16x16x32_bf16(af0, bg1, acc[0][1], 0,0,0);
    acc[1][0] = __builtin_amdgcn_mfma_f32_16x16x32_bf16(af1, bg0, acc[1][0], 0,0,0);
    acc[1][1] = __builtin_amdgcn_mfma_f32_16x16x32_bf16(af1, bg1, acc[1][1], 0,0,0);
  }

  // C/D layout (verified gfx950): col = lane&15, row = quad*4 + reg
  for (int i=0;i<2;i++){
    for (int j=0;j<2;j++){
      int gcol = n0 + wn + j*16 + mr;
      float bcol = bias[gcol];
      for (int r=0;r<4;r++){
        int grow = m0 + wm + i*16 + q*4 + r;
        float v = acc[i][j][r] + bcol;
        if (mode == 0){
          int batch = grow / L_;
          v += hs[batch*I_ + gcol];
          outb[(size_t)grow*N + gcol] = f2bf(v);
        } else {
          outf[(size_t)grow*N + gcol] = v;
        }
      }
    }
  }
}

// softmax over L (in-place on e -> alpha) + z[b,d] = sum_l alpha*fv
__global__ void softmax_z_kernel(const float* __restrict__ fv, float* __restrict__ out){
  int d = blockIdx.x*blockDim.x + threadIdx.x; // 0..D_-1
  int b = blockIdx.y;
  float* e = out + (size_t)B_*D_ + (size_t)b*L_*D_ + d;
  const float* f = fv + (size_t)b*L_*D_ + d;
  float m = -3.4e38f, s = 0.f;
  for (int l=0;l<L_;++l){
    float x = e[(size_t)l*D_];
    float nm = fmaxf(m, x);
    s = s*__expf(m-nm) + __expf(x-nm);
    m = nm;
  }
  float inv = 1.f/s;
  float z = 0.f;
  for (int l=0;l<L_;++l){
    float x = e[(size_t)l*D_];
    float a = __expf(x-m)*inv;
    e[(size_t)l*D_] = a;
    z = fmaf(a, f[(size_t)l*D_], z);
  }
  out[(size_t)b*D_ + d] = z;
}

extern "C" void kernel_launch(void* const* d_in, const int* in_sizes, int n_in,
                              void* d_out, int out_size, void* d_ws, size_t ws_size,
                              hipStream_t stream){
  (void)in_sizes; (void)n_in; (void)out_size; (void)ws_size;
  const float* fv     = (const float*)d_in[0];
  const float* hidden = (const float*)d_in[1];
  const float* W_f    = (const float*)d_in[2];
  const float* b_f    = (const float*)d_in[3];
  const float* W_h    = (const float*)d_in[4];
  const float* b_h    = (const float*)d_in[5];
  const float* W_a    = (const float*)d_in[6];
  const float* b_a    = (const float*)d_in[7];
  float* out = (float*)d_out;

  char* ws = (char*)d_ws;
  unsigned short* fv_bf = (unsigned short*)ws;                  // 51,380,224 B
  unsigned short* t_bf  = (unsigned short*)(ws + 51380224);     // 12,845,056 B
  unsigned short* WfT   = (unsigned short*)(ws + 64225280);     //  2,097,152 B
  unsigned short* WaT   = (unsigned short*)(ws + 66322432);     //  2,097,152 B
  float*          hsbuf = (float*)        (ws + 68419584);      //    131,072 B (total 68.6 MB)

  cvt_bf16_kernel<<<4096, 256, 0, stream>>>(fv, fv_bf, (B_*L_*D_)/4);
  transpose_cvt_kernel<<<dim3(I_/32, D_/32), dim3(32,8), 0, stream>>>(W_f, WfT, D_, I_); // WfT[n=I][k=D]
  transpose_cvt_kernel<<<dim3(D_/32, I_/32), dim3(32,8), 0, stream>>>(W_a, WaT, I_, D_); // WaT[n=D][k=I]
  hs_kernel<<<dim3(I_/256, B_), 256, 0, stream>>>(hidden, W_h, b_h, hsbuf);

  // GEMM1: t = bf16(fv @ W_f + b_f + hs[b])   [M, I]
  gemm_kernel<<<dim3(I_/64, M_/64), 256, 0, stream>>>(fv_bf, WfT, D_, I_, 0, b_f, hsbuf, t_bf, nullptr);
  // GEMM2: e = t @ W_a + b_a  -> written to d_out alpha region (fp32)
  gemm_kernel<<<dim3(D_/64, M_/64), 256, 0, stream>>>(t_bf, WaT, I_, D_, 1, b_a, nullptr, nullptr, out + B_*D_);

  softmax_z_kernel<<<dim3(D_/256, B_), 256, 0, stream>>>(fv, out);
}

// Round 2
// 389.772 us; speedup vs baseline: 1.0512x; 1.0512x over previous
//
#include <hip/hip_runtime.h>

#define B_ 64
#define L_ 196
#define D_ 2048
#define I_ 512
#define M_ (B_*L_)   // 12544

typedef __attribute__((ext_vector_type(8))) short bf16x8;
typedef __attribute__((ext_vector_type(4))) float f32x4;
typedef unsigned short u16;

__device__ __forceinline__ u16 f2bf(float x){
  unsigned u = __float_as_uint(x);
  u += 0x7fffu + ((u >> 16) & 1u);
  return (u16)(u >> 16);
}

__device__ __forceinline__ void gld16(const void* g, void* l){
  __builtin_amdgcn_global_load_lds(
      (const __attribute__((address_space(1))) void*)g,
      (__attribute__((address_space(3))) void*)l, 16, 0, 0);
}

// fp32 -> bf16, n4 = count/4
__global__ void cvt_bf16_kernel(const float* __restrict__ in, u16* __restrict__ out, int n4){
  int i = blockIdx.x*blockDim.x + threadIdx.x;
  int stride = gridDim.x*blockDim.x;
  for (; i < n4; i += stride){
    float4 v = ((const float4*)in)[i];
    ushort4 o;
    o.x = f2bf(v.x); o.y = f2bf(v.y); o.z = f2bf(v.z); o.w = f2bf(v.w);
    ((ushort4*)out)[i] = o;
  }
}

// in: [R,C] fp32 row-major  ->  out: [C,R] bf16 row-major
__global__ void transpose_cvt_kernel(const float* __restrict__ in, u16* __restrict__ out, int R, int C){
  __shared__ float tile[32][33];
  int c0 = blockIdx.x*32, r0 = blockIdx.y*32;
  int tx = threadIdx.x, ty = threadIdx.y; // blockDim (32,8)
  for (int i=0;i<32;i+=8)
    tile[ty+i][tx] = in[(size_t)(r0+ty+i)*C + c0 + tx];
  __syncthreads();
  for (int i=0;i<32;i+=8)
    out[(size_t)(c0+ty+i)*R + r0 + tx] = f2bf(tile[tx][ty+i]);
}

// hs[b][n] = b_h[n] + sum_k hidden[b][k] * W_h[k][n]   (unroll-4 partial sums)
__global__ void hs_kernel(const float* __restrict__ hidden, const float* __restrict__ Wh,
                          const float* __restrict__ bh, float* __restrict__ hs){
  int n = blockIdx.x*blockDim.x + threadIdx.x; // 0..I_-1
  int b = blockIdx.y;
  const float* hrow = hidden + b*I_;
  float a0=0.f,a1=0.f,a2=0.f,a3=0.f;
  for (int k=0;k<I_;k+=4){
    a0 = fmaf(hrow[k+0], Wh[(size_t)(k+0)*I_ + n], a0);
    a1 = fmaf(hrow[k+1], Wh[(size_t)(k+1)*I_ + n], a1);
    a2 = fmaf(hrow[k+2], Wh[(size_t)(k+2)*I_ + n], a2);
    a3 = fmaf(hrow[k+3], Wh[(size_t)(k+3)*I_ + n], a3);
  }
  hs[b*I_ + n] = bh[n] + ((a0+a1)+(a2+a3));
}

// C[M,N] = A[M,K](bf16) x Bt[N,K](bf16)^T
// 128x128 block tile, BK=32, 4 waves (2x2), each wave 64x64 = 4x4 of 16x16x32 MFMA.
// Staging via global_load_lds width=16 (wave-uniform LDS base + lane*16 — no padding allowed).
// Bank-conflict fix: XOR swizzle; LDS 16B-chunk for (row,kc) = row*4 + (kc ^ ((row>>2)&3)).
//   frag-read chunk%8 = 4*(row&1) + kc_swz -> exactly 2 lanes/chunk per quad = 2-way = free (m136).
// mode 0: outb = bf16(acc + bias[n] + hs[m/L_][n]);  mode 1: outf = acc + bias[n]
__launch_bounds__(256)
__global__ void gemm128_kernel(const u16* __restrict__ A,
                               const u16* __restrict__ Bt,
                               int K, int N, int mode,
                               const float* __restrict__ bias,
                               const float* __restrict__ hs,
                               u16* __restrict__ outb,
                               float* __restrict__ outf)
{
  __shared__ __align__(16) u16 Als[128*32];  // 8 KB, swizzled chunk layout
  __shared__ __align__(16) u16 Bls[128*32];  // 8 KB

  const int tid  = threadIdx.x;
  const int lane = tid & 63;
  const int wave = tid >> 6;
  const int m0 = blockIdx.y * 128;
  const int n0 = blockIdx.x * 128;

  const int wrow = (wave & 1) * 64;
  const int wcol = (wave >> 1) * 64;
  const int q  = lane >> 4;
  const int mr = lane & 15;

  // Staging: 8 issues of 1024B per tile; wave w takes issues j0=2w, j0+1 for both A and B.
  // Issue j, lane: chunk c = j*64+lane -> row = j*16 + (lane>>2), kc_swz = lane&3,
  // global kc = kc_swz ^ ((row>>2)&3).
  const int j0 = wave * 2;
  const int r0i = j0*16     + (lane>>2);
  const int r1i = (j0+1)*16 + (lane>>2);
  const int kc0 = (lane&3) ^ ((r0i>>2)&3);
  const int kc1 = (lane&3) ^ ((r1i>>2)&3);
  const u16* Ag0 = A  + (size_t)(m0 + r0i)*K + kc0*8;
  const u16* Ag1 = A  + (size_t)(m0 + r1i)*K + kc1*8;
  const u16* Bg0 = Bt + (size_t)(n0 + r0i)*K + kc0*8;
  const u16* Bg1 = Bt + (size_t)(n0 + r1i)*K + kc1*8;
  u16* Al0 = Als + (size_t)j0*512;      // wave-uniform LDS bases (512 u16 = 1024 B / issue)
  u16* Al1 = Als + (size_t)(j0+1)*512;
  u16* Bl0 = Bls + (size_t)j0*512;
  u16* Bl1 = Bls + (size_t)(j0+1)*512;

  // Frag LDS offsets (u16 units), k-invariant
  int aoff[4], boff[4];
  #pragma unroll
  for (int t=0;t<4;t++){
    int R = wrow + t*16 + mr;
    aoff[t] = (R*4 + (q ^ ((R>>2)&3)))*8;
    int C = wcol + t*16 + mr;
    boff[t] = (C*4 + (q ^ ((C>>2)&3)))*8;
  }

  f32x4 acc[4][4];
  #pragma unroll
  for (int i=0;i<4;i++)
    #pragma unroll
    for (int j=0;j<4;j++) acc[i][j] = (f32x4){0.f,0.f,0.f,0.f};

  for (int k0 = 0; k0 < K; k0 += 32){
    __syncthreads();                 // prior frag reads done before overwrite
    gld16(Ag0 + k0, Al0);
    gld16(Ag1 + k0, Al1);
    gld16(Bg0 + k0, Bl0);
    gld16(Bg1 + k0, Bl1);
    __syncthreads();                 // vmcnt(0) drain + barrier: tiles visible
    bf16x8 af[4], bg[4];
    #pragma unroll
    for (int t=0;t<4;t++){
      af[t] = *(const bf16x8*)(Als + aoff[t]);
      bg[t] = *(const bf16x8*)(Bls + boff[t]);
    }
    #pragma unroll
    for (int i=0;i<4;i++)
      #pragma unroll
      for (int j=0;j<4;j++)
        acc[i][j] = __builtin_amdgcn_mfma_f32_16x16x32_bf16(af[i], bg[j], acc[i][j], 0,0,0);
  }

  // C/D layout (verified gfx950): col = lane&15, row = quad*4 + reg
  #pragma unroll
  for (int i=0;i<4;i++){
    #pragma unroll
    for (int j=0;j<4;j++){
      int gcol = n0 + wcol + j*16 + mr;
      float bcol = bias[gcol];
      #pragma unroll
      for (int r=0;r<4;r++){
        int grow = m0 + wrow + i*16 + q*4 + r;
        float v = acc[i][j][r] + bcol;
        if (mode == 0){
          int batch = grow / L_;
          outb[(size_t)grow*N + gcol] = f2bf(v + hs[batch*I_ + gcol]);
        } else {
          outf[(size_t)grow*N + gcol] = v;
        }
      }
    }
  }
}

// softmax over L (in-place on e -> alpha) + z[b,d] = sum_l alpha*fv
__global__ void softmax_z_kernel(const float* __restrict__ fv, float* __restrict__ out){
  int d = blockIdx.x*blockDim.x + threadIdx.x; // 0..D_-1
  int b = blockIdx.y;
  float* e = out + (size_t)B_*D_ + (size_t)b*L_*D_ + d;
  const float* f = fv + (size_t)b*L_*D_ + d;
  float m = -3.4e38f, s = 0.f;
  for (int l=0;l<L_;++l){
    float x = e[(size_t)l*D_];
    float nm = fmaxf(m, x);
    s = s*__expf(m-nm) + __expf(x-nm);
    m = nm;
  }
  float inv = 1.f/s;
  float z = 0.f;
  for (int l=0;l<L_;++l){
    float x = e[(size_t)l*D_];
    float a = __expf(x-m)*inv;
    e[(size_t)l*D_] = a;
    z = fmaf(a, f[(size_t)l*D_], z);
  }
  out[(size_t)b*D_ + d] = z;
}

extern "C" void kernel_launch(void* const* d_in, const int* in_sizes, int n_in,
                              void* d_out, int out_size, void* d_ws, size_t ws_size,
                              hipStream_t stream){
  (void)in_sizes; (void)n_in; (void)out_size; (void)ws_size;
  const float* fv     = (const float*)d_in[0];
  const float* hidden = (const float*)d_in[1];
  const float* W_f    = (const float*)d_in[2];
  const float* b_f    = (const float*)d_in[3];
  const float* W_h    = (const float*)d_in[4];
  const float* b_h    = (const float*)d_in[5];
  const float* W_a    = (const float*)d_in[6];
  const float* b_a    = (const float*)d_in[7];
  float* out = (float*)d_out;

  char* ws = (char*)d_ws;
  u16*   fv_bf = (u16*)ws;                     // 51,380,224 B
  u16*   t_bf  = (u16*)(ws + 51380224);        // 12,845,056 B
  u16*   WfT   = (u16*)(ws + 64225280);        //  2,097,152 B
  u16*   WaT   = (u16*)(ws + 66322432);        //  2,097,152 B
  float* hsbuf = (float*)(ws + 68419584);      //    131,072 B (total 68.6 MB)

  cvt_bf16_kernel<<<4096, 256, 0, stream>>>(fv, fv_bf, (B_*L_*D_)/4);
  transpose_cvt_kernel<<<dim3(I_/32, D_/32), dim3(32,8), 0, stream>>>(W_f, WfT, D_, I_); // WfT[n=I][k=D]
  transpose_cvt_kernel<<<dim3(D_/32, I_/32), dim3(32,8), 0, stream>>>(W_a, WaT, I_, D_); // WaT[n=D][k=I]
  hs_kernel<<<dim3(I_/256, B_), 256, 0, stream>>>(hidden, W_h, b_h, hsbuf);

  // GEMM1: t = bf16(fv @ W_f + b_f + hs[b])   [M, I]
  gemm128_kernel<<<dim3(I_/128, M_/128), 256, 0, stream>>>(fv_bf, WfT, D_, I_, 0, b_f, hsbuf, t_bf, nullptr);
  // GEMM2: e = t @ W_a + b_a -> d_out alpha region (fp32)
  gemm128_kernel<<<dim3(D_/128, M_/128), 256, 0, stream>>>(t_bf, WaT, I_, D_, 1, b_a, nullptr, nullptr, out + B_*D_);

  softmax_z_kernel<<<dim3(D_/256, B_), 256, 0, stream>>>(fv, out);
}

// Round 3
// 372.314 us; speedup vs baseline: 1.1005x; 1.0469x over previous
//
#include <hip/hip_runtime.h>

#define B_ 64
#define L_ 196
#define D_ 2048
#define I_ 512
#define M_ (B_*L_)   // 12544

typedef __attribute__((ext_vector_type(8))) short bf16x8;
typedef __attribute__((ext_vector_type(4))) float f32x4;
typedef unsigned short u16;

__device__ __forceinline__ u16 f2bf(float x){
  unsigned u = __float_as_uint(x);
  u += 0x7fffu + ((u >> 16) & 1u);
  return (u16)(u >> 16);
}

__device__ __forceinline__ void gld16(const void* g, void* l){
  __builtin_amdgcn_global_load_lds(
      (const __attribute__((address_space(1))) void*)g,
      (__attribute__((address_space(3))) void*)l, 16, 0, 0);
}

// fp32 -> bf16, n4 = count/4
__global__ void cvt_bf16_kernel(const float* __restrict__ in, u16* __restrict__ out, int n4){
  int i = blockIdx.x*blockDim.x + threadIdx.x;
  int stride = gridDim.x*blockDim.x;
  for (; i < n4; i += stride){
    float4 v = ((const float4*)in)[i];
    ushort4 o;
    o.x = f2bf(v.x); o.y = f2bf(v.y); o.z = f2bf(v.z); o.w = f2bf(v.w);
    ((ushort4*)out)[i] = o;
  }
}

// in: [R,C] fp32 row-major  ->  out: [C,R] bf16 row-major
__global__ void transpose_cvt_kernel(const float* __restrict__ in, u16* __restrict__ out, int R, int C){
  __shared__ float tile[32][33];
  int c0 = blockIdx.x*32, r0 = blockIdx.y*32;
  int tx = threadIdx.x, ty = threadIdx.y; // blockDim (32,8)
  for (int i=0;i<32;i+=8)
    tile[ty+i][tx] = in[(size_t)(r0+ty+i)*C + c0 + tx];
  __syncthreads();
  for (int i=0;i<32;i+=8)
    out[(size_t)(c0+ty+i)*R + r0 + tx] = f2bf(tile[tx][ty+i]);
}

// hs[b][n] = b_h[n] + sum_k hidden[b][k] * W_h[k][n]
__global__ void hs_kernel(const float* __restrict__ hidden, const float* __restrict__ Wh,
                          const float* __restrict__ bh, float* __restrict__ hs){
  int n = blockIdx.x*blockDim.x + threadIdx.x;
  int b = blockIdx.y;
  const float* hrow = hidden + b*I_;
  float a0=0.f,a1=0.f,a2=0.f,a3=0.f;
  for (int k=0;k<I_;k+=4){
    a0 = fmaf(hrow[k+0], Wh[(size_t)(k+0)*I_ + n], a0);
    a1 = fmaf(hrow[k+1], Wh[(size_t)(k+1)*I_ + n], a1);
    a2 = fmaf(hrow[k+2], Wh[(size_t)(k+2)*I_ + n], a2);
    a3 = fmaf(hrow[k+3], Wh[(size_t)(k+3)*I_ + n], a3);
  }
  hs[b*I_ + n] = bh[n] + ((a0+a1)+(a2+a3));
}

// C[M,N] = A[M,K](bf16) x Bt[N,K](bf16)^T.
// Tile 128(M) x BN, BK=64. 4 waves 2x2; wave = 64 x BN/2 of 16x16x32 MFMA.
// Staging: global_load_lds w16, XOR-swizzled chunks (chunk' = kc ^ (row&7)) -> frag
// ds_read_b128 hits 2 lanes/bank (free), global side stays 128B-contiguous per row.
// MODE 0: outb = bf16(acc + bias[n] + hs[m/L_][n]);  MODE 1: outf = acc + bias[n]
template<int BN, int K, int MODE, int NLD>
__launch_bounds__(256)
__global__ void gemm_kernel(const u16* __restrict__ A, const u16* __restrict__ Bt,
                            const float* __restrict__ bias, const float* __restrict__ hs,
                            u16* __restrict__ outb, float* __restrict__ outf)
{
  constexpr int BM = 128, BK = 64;
  constexpr int NF = BN/32;        // n-frags per wave (2 or 4)
  constexpr int AW = 4;            // A gld16 issues per wave (16 total)
  constexpr int BW = BN/32;        // B gld16 issues per wave

  __shared__ __align__(16) u16 Als[BM*BK];
  __shared__ __align__(16) u16 Bls[BN*BK];

  const int tid = threadIdx.x, lane = tid & 63, wave = tid >> 6;
  const int m0 = blockIdx.y * BM, n0 = blockIdx.x * BN;
  const int q = lane >> 4, mr = lane & 15;
  const int wrow = (wave & 1) * 64;
  const int wcol = (wave >> 1) * (BN/2);

  const int lrow = lane >> 3;            // 0..7 (row within 8-row issue slab)
  const int kc   = (lane & 7) ^ lrow;    // swizzled 16B-chunk column

  const u16* Ag[AW]; u16* Al[AW];
  #pragma unroll
  for (int u=0; u<AW; ++u){
    int j = wave*AW + u;
    Ag[u] = A + (size_t)(m0 + j*8 + lrow)*K + kc*8;
    Al[u] = Als + j*512;
  }
  const u16* Bg[BW]; u16* Bl[BW];
  #pragma unroll
  for (int u=0; u<BW; ++u){
    int j = wave*BW + u;
    Bg[u] = Bt + (size_t)(n0 + j*8 + lrow)*K + kc*8;
    Bl[u] = Bls + j*512;
  }

  int aoff[4][2], boff[NF][2];
  #pragma unroll
  for (int i=0;i<4;i++)
    #pragma unroll
    for (int s=0;s<2;s++){
      int R = wrow + i*16 + mr;
      aoff[i][s] = R*64 + (((s*4+q) ^ (mr&7))*8);
    }
  #pragma unroll
  for (int j=0;j<NF;j++)
    #pragma unroll
    for (int s=0;s<2;s++){
      int C = wcol + j*16 + mr;
      boff[j][s] = C*64 + (((s*4+q) ^ (mr&7))*8);
    }

  f32x4 acc[4][NF];
  #pragma unroll
  for (int i=0;i<4;i++)
    #pragma unroll
    for (int j=0;j<NF;j++) acc[i][j] = (f32x4){0.f,0.f,0.f,0.f};

  for (int k0=0; k0<K; k0+=BK){
    __syncthreads();
    #pragma unroll
    for (int u=0;u<AW;++u) gld16(Ag[u] + k0, Al[u]);
    #pragma unroll
    for (int u=0;u<BW;++u) gld16(Bg[u] + k0, Bl[u]);
    __syncthreads();
    #pragma unroll
    for (int s=0;s<2;s++){
      bf16x8 af[4], bg[NF];
      #pragma unroll
      for (int i=0;i<4;i++) af[i] = *(const bf16x8*)(Als + aoff[i][s]);
      #pragma unroll
      for (int j=0;j<NF;j++) bg[j] = *(const bf16x8*)(Bls + boff[j][s]);
      #pragma unroll
      for (int i=0;i<4;i++)
        #pragma unroll
        for (int j=0;j<NF;j++)
          acc[i][j] = __builtin_amdgcn_mfma_f32_16x16x32_bf16(af[i], bg[j], acc[i][j], 0,0,0);
    }
  }

  // C/D layout (verified gfx950): col = lane&15, row = quad*4 + reg
  #pragma unroll
  for (int i=0;i<4;i++){
    #pragma unroll
    for (int j=0;j<NF;j++){
      int gcol = n0 + wcol + j*16 + mr;
      float bcol = bias[gcol];
      #pragma unroll
      for (int r=0;r<4;r++){
        int grow = m0 + wrow + i*16 + q*4 + r;
        float v = acc[i][j][r] + bcol;
        if (MODE == 0){
          int batch = grow / L_;
          outb[(size_t)grow*NLD + gcol] = f2bf(v + hs[batch*I_ + gcol]);
        } else {
          outf[(size_t)grow*NLD + gcol] = v;
        }
      }
    }
  }
}

// softmax over L (in-place e -> alpha) + z[b,d] = sum_l alpha*fv.
// Block: 64 d-columns x 4 L-groups (49 values each, register-resident; e read ONCE).
__launch_bounds__(256)
__global__ void softmax_z_kernel(const float* __restrict__ fv, float* __restrict__ out){
  __shared__ float red[4][64];
  const int dl = threadIdx.x & 63, g = threadIdx.x >> 6;
  const int d = blockIdx.x*64 + dl, b = blockIdx.y;
  float* e = out + (size_t)B_*D_ + (size_t)b*L_*D_ + d;
  const float* f = fv + (size_t)b*L_*D_ + d;

  float ev[49];
  float m = -3.4e38f;
  #pragma unroll
  for (int j=0;j<49;j++){
    ev[j] = e[(size_t)(g*49+j)*D_];
    m = fmaxf(m, ev[j]);
  }
  red[g][dl] = m;
  __syncthreads();
  m = fmaxf(fmaxf(red[0][dl],red[1][dl]), fmaxf(red[2][dl],red[3][dl]));
  __syncthreads();

  float s = 0.f;
  #pragma unroll
  for (int j=0;j<49;j++){ ev[j] = __expf(ev[j]-m); s += ev[j]; }
  red[g][dl] = s;
  __syncthreads();
  s = (red[0][dl]+red[1][dl]) + (red[2][dl]+red[3][dl]);
  __syncthreads();

  float inv = 1.f/s, z = 0.f;
  #pragma unroll
  for (int j=0;j<49;j++){
    float a = ev[j]*inv;
    e[(size_t)(g*49+j)*D_] = a;
    z = fmaf(a, f[(size_t)(g*49+j)*D_], z);
  }
  red[g][dl] = z;
  __syncthreads();
  if (g==0)
    out[(size_t)b*D_ + dl + blockIdx.x*64] = (red[0][dl]+red[1][dl]) + (red[2][dl]+red[3][dl]);
}

extern "C" void kernel_launch(void* const* d_in, const int* in_sizes, int n_in,
                              void* d_out, int out_size, void* d_ws, size_t ws_size,
                              hipStream_t stream){
  (void)in_sizes; (void)n_in; (void)out_size; (void)ws_size;
  const float* fv     = (const float*)d_in[0];
  const float* hidden = (const float*)d_in[1];
  const float* W_f    = (const float*)d_in[2];
  const float* b_f    = (const float*)d_in[3];
  const float* W_h    = (const float*)d_in[4];
  const float* b_h    = (const float*)d_in[5];
  const float* W_a    = (const float*)d_in[6];
  const float* b_a    = (const float*)d_in[7];
  float* out = (float*)d_out;

  char* ws = (char*)d_ws;
  u16*   fv_bf = (u16*)ws;                     // 51,380,224 B
  u16*   t_bf  = (u16*)(ws + 51380224);        // 12,845,056 B
  u16*   WfT   = (u16*)(ws + 64225280);        //  2,097,152 B
  u16*   WaT   = (u16*)(ws + 66322432);        //  2,097,152 B
  float* hsbuf = (float*)(ws + 68419584);      //    131,072 B (total 68.6 MB)

  cvt_bf16_kernel<<<4096, 256, 0, stream>>>(fv, fv_bf, (B_*L_*D_)/4);
  transpose_cvt_kernel<<<dim3(I_/32, D_/32), dim3(32,8), 0, stream>>>(W_f, WfT, D_, I_);
  transpose_cvt_kernel<<<dim3(D_/32, I_/32), dim3(32,8), 0, stream>>>(W_a, WaT, I_, D_);
  hs_kernel<<<dim3(I_/256, B_), 256, 0, stream>>>(hidden, W_h, b_h, hsbuf);

  // GEMM1: t = bf16(fv @ W_f + b_f + hs[b])  [M, I];  tile 128x64, 784 blocks
  gemm_kernel<64, D_, 0, I_><<<dim3(I_/64, M_/128), 256, 0, stream>>>(fv_bf, WfT, b_f, hsbuf, t_bf, nullptr);
  // GEMM2: e = t @ W_a + b_a -> d_out alpha region; tile 128x128, 1568 blocks
  gemm_kernel<128, I_, 1, D_><<<dim3(D_/128, M_/128), 256, 0, stream>>>(t_bf, WaT, b_a, nullptr, nullptr, out + B_*D_);

  softmax_z_kernel<<<dim3(D_/64, B_), 256, 0, stream>>>(fv, out);
}

// Round 4
// 358.726 us; speedup vs baseline: 1.1422x; 1.0379x over previous
//
#include <hip/hip_runtime.h>

#define B_ 64
#define L_ 196
#define D_ 2048
#define I_ 512
#define M_ (B_*L_)   // 12544

typedef __attribute__((ext_vector_type(8))) short bf16x8;
typedef __attribute__((ext_vector_type(4))) float f32x4;
typedef unsigned short u16;

__device__ __forceinline__ u16 f2bf(float x){
  unsigned u = __float_as_uint(x);
  u += 0x7fffu + ((u >> 16) & 1u);
  return (u16)(u >> 16);
}

__device__ __forceinline__ void gld16(const void* g, void* l){
  __builtin_amdgcn_global_load_lds(
      (const __attribute__((address_space(1))) void*)g,
      (__attribute__((address_space(3))) void*)l, 16, 0, 0);
}

// gfx9 waitcnt imm: vmcnt[3:0]=bits3:0, expcnt=bits6:4, lgkmcnt=bits11:8, vmcnt[5:4]=bits15:14
template<int N> __device__ __forceinline__ void wait_vm(){
  __builtin_amdgcn_s_waitcnt((N&15) | ((N&48)<<10) | (7<<4) | (15<<8));
}
__device__ __forceinline__ void wait_lgkm0(){
  __builtin_amdgcn_s_waitcnt(15 | (48<<10) | (7<<4));   // vmcnt=63 (no wait), lgkmcnt=0
}
__device__ __forceinline__ void bar(){
  asm volatile("" ::: "memory");
  __builtin_amdgcn_s_barrier();
  asm volatile("" ::: "memory");
}

// fp32 -> bf16, n4 = count/4
__global__ void cvt_bf16_kernel(const float* __restrict__ in, u16* __restrict__ out, int n4){
  int i = blockIdx.x*blockDim.x + threadIdx.x;
  int stride = gridDim.x*blockDim.x;
  for (; i < n4; i += stride){
    float4 v = ((const float4*)in)[i];
    ushort4 o;
    o.x = f2bf(v.x); o.y = f2bf(v.y); o.z = f2bf(v.z); o.w = f2bf(v.w);
    ((ushort4*)out)[i] = o;
  }
}

// in: [R,C] fp32 row-major  ->  out: [C,R] bf16 row-major
__global__ void transpose_cvt_kernel(const float* __restrict__ in, u16* __restrict__ out, int R, int C){
  __shared__ float tile[32][33];
  int c0 = blockIdx.x*32, r0 = blockIdx.y*32;
  int tx = threadIdx.x, ty = threadIdx.y; // blockDim (32,8)
  for (int i=0;i<32;i+=8)
    tile[ty+i][tx] = in[(size_t)(r0+ty+i)*C + c0 + tx];
  __syncthreads();
  for (int i=0;i<32;i+=8)
    out[(size_t)(c0+ty+i)*R + r0 + tx] = f2bf(tile[tx][ty+i]);
}

// hs[b][n] = b_h[n] + sum_k hidden[b][k] * W_h[k][n]
__global__ void hs_kernel(const float* __restrict__ hidden, const float* __restrict__ Wh,
                          const float* __restrict__ bh, float* __restrict__ hs){
  int n = blockIdx.x*blockDim.x + threadIdx.x;
  int b = blockIdx.y;
  const float* hrow = hidden + b*I_;
  float a0=0.f,a1=0.f,a2=0.f,a3=0.f;
  for (int k=0;k<I_;k+=4){
    a0 = fmaf(hrow[k+0], Wh[(size_t)(k+0)*I_ + n], a0);
    a1 = fmaf(hrow[k+1], Wh[(size_t)(k+1)*I_ + n], a1);
    a2 = fmaf(hrow[k+2], Wh[(size_t)(k+2)*I_ + n], a2);
    a3 = fmaf(hrow[k+3], Wh[(size_t)(k+3)*I_ + n], a3);
  }
  hs[b*I_ + n] = bh[n] + ((a0+a1)+(a2+a3));
}

// GEMM1: t = bf16(fv_bf @ WfT^T + b_f + hs[batch])   [M,512]
// BM=64, BN=128, BK=64, double-buffered LDS, fine-grained vmcnt (never drains in-flight prefetch).
// Per iter per wave: 6 gld16 prefetch, 12 ds_read_b128, 16 MFMA.
__launch_bounds__(256)
__global__ void gemm1_kernel(const u16* __restrict__ A, const u16* __restrict__ Bt,
                             const float* __restrict__ bias, const float* __restrict__ hs,
                             u16* __restrict__ outb)
{
  constexpr int K = D_, BK = 64, NIT = K/BK;     // 32
  __shared__ __align__(16) u16 Als[2][64*64];    // 8 KB each
  __shared__ __align__(16) u16 Bls[2][128*64];   // 16 KB each

  const int tid = threadIdx.x, lane = tid&63, wave = tid>>6;
  const int m0 = blockIdx.y*64, n0 = blockIdx.x*128;
  const int q = lane>>4, mr = lane&15;
  const int wrow = (wave&1)*32, wcol = (wave>>1)*64;
  const int lrow = lane>>3, kc = (lane&7)^lrow;  // XOR swizzle (R3: 0 conflicts)

  const u16* Ag[2]; int Alo[2];
  #pragma unroll
  for (int u=0;u<2;++u){ int j = wave*2+u; Ag[u] = A + (size_t)(m0 + j*8 + lrow)*K + kc*8; Alo[u] = j*512; }
  const u16* Bg[4]; int Blo[4];
  #pragma unroll
  for (int u=0;u<4;++u){ int j = wave*4+u; Bg[u] = Bt + (size_t)(n0 + j*8 + lrow)*K + kc*8; Blo[u] = j*512; }

  int aoff[2][2], boff[4][2];
  #pragma unroll
  for (int i=0;i<2;i++)
    #pragma unroll
    for (int s=0;s<2;s++){ int R = wrow + i*16 + mr; aoff[i][s] = R*64 + (((s*4+q) ^ (mr&7))*8); }
  #pragma unroll
  for (int j=0;j<4;j++)
    #pragma unroll
    for (int s=0;s<2;s++){ int C = wcol + j*16 + mr; boff[j][s] = C*64 + (((s*4+q) ^ (mr&7))*8); }

  f32x4 acc[2][4];
  #pragma unroll
  for (int i=0;i<2;i++)
    #pragma unroll
    for (int j=0;j<4;j++) acc[i][j] = (f32x4){0.f,0.f,0.f,0.f};

  // preload tiles 0,1 (12 outstanding)
  #pragma unroll
  for (int u=0;u<2;++u) gld16(Ag[u],    &Als[0][Alo[u]]);
  #pragma unroll
  for (int u=0;u<4;++u) gld16(Bg[u],    &Bls[0][Blo[u]]);
  #pragma unroll
  for (int u=0;u<2;++u) gld16(Ag[u]+BK, &Als[1][Alo[u]]);
  #pragma unroll
  for (int u=0;u<4;++u) gld16(Bg[u]+BK, &Bls[1][Blo[u]]);

  for (int i=0;i<NIT;++i){
    if (i+1<NIT) wait_vm<6>(); else wait_vm<0>();  // drain ONLY tile i
    bar();
    const u16* Ab = Als[i&1];
    const u16* Bb = Bls[i&1];
    bf16x8 af[2][2], bg[4][2];
    #pragma unroll
    for (int s=0;s<2;s++){
      #pragma unroll
      for (int i2=0;i2<2;i2++) af[i2][s] = *(const bf16x8*)(Ab + aoff[i2][s]);
      #pragma unroll
      for (int j=0;j<4;j++)    bg[j][s]  = *(const bf16x8*)(Bb + boff[j][s]);
    }
    wait_lgkm0();      // frags in regs
    bar();             // buf[i&1] free
    if (i+2<NIT){
      int k0 = (i+2)*BK;
      #pragma unroll
      for (int u=0;u<2;++u) gld16(Ag[u]+k0, &Als[i&1][Alo[u]]);
      #pragma unroll
      for (int u=0;u<4;++u) gld16(Bg[u]+k0, &Bls[i&1][Blo[u]]);
    }
    #pragma unroll
    for (int s=0;s<2;s++)
      #pragma unroll
      for (int i2=0;i2<2;i2++)
        #pragma unroll
        for (int j=0;j<4;j++)
          acc[i2][j] = __builtin_amdgcn_mfma_f32_16x16x32_bf16(af[i2][s], bg[j][s], acc[i2][j], 0,0,0);
  }

  // C/D layout: col = lane&15, row = quad*4 + reg
  #pragma unroll
  for (int i2=0;i2<2;i2++){
    #pragma unroll
    for (int j=0;j<4;j++){
      int gcol = n0 + wcol + j*16 + mr;
      float bcol = bias[gcol];
      #pragma unroll
      for (int r=0;r<4;r++){
        int grow = m0 + wrow + i2*16 + q*4 + r;
        int batch = grow / L_;
        outb[(size_t)grow*I_ + gcol] = f2bf(acc[i2][j][r] + bcol + hs[batch*I_ + gcol]);
      }
    }
  }
}

// Fused GEMM2 + softmax + z. Block = (batch b, 128 e-cols). M-tile = all 196 rows
// (13 frags; frag 12 rows 196..207 masked, valid only q==0). e stays in registers.
// Per column: max/sum reduced over regs then __shfl_xor(16/32) across q-lanes.
// alpha written once (fp32); z from fp32 fv, written exactly (block owns (b, d-slice)).
__launch_bounds__(256)
__global__ void gemm2_fused_kernel(const u16* __restrict__ T, const u16* __restrict__ Wa,
                                   const float* __restrict__ b_a, const float* __restrict__ fv,
                                   float* __restrict__ out)
{
  constexpr int K = I_, BK = 32, NIT = K/BK;     // 16
  __shared__ __align__(16) u16 Als[2][256*32];   // 16 KB each (rows 208..255 staged, unused)
  __shared__ __align__(16) u16 Bls[2][128*32];   // 8 KB each

  const int tid = threadIdx.x, lane = tid&63, wave = tid>>6;
  const int b = blockIdx.y, n0 = blockIdx.x*128;
  const int q = lane>>4, mr = lane&15;
  const int wcol = wave*32;                      // waves split N only; all share all rows
  const int l16 = lane>>2, kc4 = (lane&3)^(l16&3);

  // A: 16 issues of 16 rows x 32 k; wave takes 4
  const u16* Ag[4]; int Alo[4];
  #pragma unroll
  for (int u=0;u<4;++u){
    int j = wave*4+u;
    int grow = b*L_ + j*16 + l16; if (grow > M_-1) grow = M_-1;   // clamp (masked later)
    Ag[u] = T + (size_t)grow*K + kc4*8; Alo[u] = j*512;
  }
  // B: 8 issues; wave takes 2
  const u16* Bg[2]; int Blo[2];
  #pragma unroll
  for (int u=0;u<2;++u){
    int j = wave*2+u;
    Bg[u] = Wa + (size_t)(n0 + j*16 + l16)*K + kc4*8; Blo[u] = j*512;
  }

  const int abase = mr*32 + ((q ^ (mr&3))*8);    // + i*512 per frag
  int boff[2];
  #pragma unroll
  for (int j=0;j<2;j++){ int C = wcol + j*16 + mr; boff[j] = C*32 + ((q ^ (mr&3))*8); }

  f32x4 acc[13][2];
  #pragma unroll
  for (int i=0;i<13;i++){ acc[i][0] = (f32x4){0,0,0,0}; acc[i][1] = (f32x4){0,0,0,0}; }

  // preload tiles 0,1 (12 outstanding)
  #pragma unroll
  for (int u=0;u<4;++u) gld16(Ag[u],    &Als[0][Alo[u]]);
  #pragma unroll
  for (int u=0;u<2;++u) gld16(Bg[u],    &Bls[0][Blo[u]]);
  #pragma unroll
  for (int u=0;u<4;++u) gld16(Ag[u]+BK, &Als[1][Alo[u]]);
  #pragma unroll
  for (int u=0;u<2;++u) gld16(Bg[u]+BK, &Bls[1][Blo[u]]);

  for (int it=0; it<NIT; ++it){
    if (it+1<NIT) wait_vm<6>(); else wait_vm<0>();
    bar();
    const u16* Ab = Als[it&1];
    const u16* Bb = Bls[it&1];
    bf16x8 bg0 = *(const bf16x8*)(Bb + boff[0]);
    bf16x8 bg1 = *(const bf16x8*)(Bb + boff[1]);
    bf16x8 af[13];
    #pragma unroll
    for (int i=0;i<13;++i) af[i] = *(const bf16x8*)(Ab + abase + i*512);
    wait_lgkm0();
    bar();
    if (it+2<NIT){
      int k0 = (it+2)*BK;
      #pragma unroll
      for (int u=0;u<4;++u) gld16(Ag[u]+k0, &Als[it&1][Alo[u]]);
      #pragma unroll
      for (int u=0;u<2;++u) gld16(Bg[u]+k0, &Bls[it&1][Blo[u]]);
    }
    #pragma unroll
    for (int i=0;i<13;++i){
      acc[i][0] = __builtin_amdgcn_mfma_f32_16x16x32_bf16(af[i], bg0, acc[i][0], 0,0,0);
      acc[i][1] = __builtin_amdgcn_mfma_f32_16x16x32_bf16(af[i], bg1, acc[i][1], 0,0,0);
    }
  }

  // ---- fused epilogue: e = acc + b_a; softmax over rows; alpha + z ----
  const bool v12 = (q == 0);                     // frag 12: rows 192..195 valid only for q==0
  int col[2] = { n0 + wcol + mr, n0 + wcol + 16 + mr };
  float bc[2] = { b_a[col[0]], b_a[col[1]] };
  #pragma unroll
  for (int i=0;i<13;++i)
    #pragma unroll
    for (int j=0;j<2;++j)
      #pragma unroll
      for (int r=0;r<4;++r) acc[i][j][r] += bc[j];

  float mx[2], sm[2];
  #pragma unroll
  for (int j=0;j<2;++j){
    float m = -3.4e38f;
    #pragma unroll
    for (int i=0;i<12;++i)
      #pragma unroll
      for (int r=0;r<4;++r) m = fmaxf(m, acc[i][j][r]);
    if (v12)
      #pragma unroll
      for (int r=0;r<4;++r) m = fmaxf(m, acc[12][j][r]);
    m = fmaxf(m, __shfl_xor(m, 16));
    m = fmaxf(m, __shfl_xor(m, 32));
    mx[j] = m;
    float s = 0.f;
    #pragma unroll
    for (int i=0;i<12;++i)
      #pragma unroll
      for (int r=0;r<4;++r){ float e = __expf(acc[i][j][r]-m); acc[i][j][r] = e; s += e; }
    if (v12)
      #pragma unroll
      for (int r=0;r<4;++r){ float e = __expf(acc[12][j][r]-m); acc[12][j][r] = e; s += e; }
    s += __shfl_xor(s, 16);
    s += __shfl_xor(s, 32);
    sm[j] = s;
  }
  float inv[2] = { 1.f/sm[0], 1.f/sm[1] };

  float* alpha = out + (size_t)B_*D_ + (size_t)b*L_*D_;
  const float* fvb = fv + (size_t)b*L_*D_;
  float z[2] = {0.f, 0.f};
  #pragma unroll
  for (int i=0;i<13;++i){
    if (i < 12 || v12){
      #pragma unroll
      for (int r=0;r<4;++r){
        int row = i*16 + q*4 + r;               // < 196 when valid
        #pragma unroll
        for (int j=0;j<2;++j){
          float a = acc[i][j][r] * inv[j];
          alpha[(size_t)row*D_ + col[j]] = a;
          z[j] = fmaf(a, fvb[(size_t)row*D_ + col[j]], z[j]);
        }
      }
    }
  }
  #pragma unroll
  for (int j=0;j<2;++j){
    z[j] += __shfl_xor(z[j], 16);
    z[j] += __shfl_xor(z[j], 32);
  }
  if (q == 0){
    out[(size_t)b*D_ + col[0]] = z[0];
    out[(size_t)b*D_ + col[1]] = z[1];
  }
}

extern "C" void kernel_launch(void* const* d_in, const int* in_sizes, int n_in,
                              void* d_out, int out_size, void* d_ws, size_t ws_size,
                              hipStream_t stream){
  (void)in_sizes; (void)n_in; (void)out_size; (void)ws_size;
  const float* fv     = (const float*)d_in[0];
  const float* hidden = (const float*)d_in[1];
  const float* W_f    = (const float*)d_in[2];
  const float* b_f    = (const float*)d_in[3];
  const float* W_h    = (const float*)d_in[4];
  const float* b_h    = (const float*)d_in[5];
  const float* W_a    = (const float*)d_in[6];
  const float* b_a    = (const float*)d_in[7];
  float* out = (float*)d_out;

  char* ws = (char*)d_ws;
  u16*   fv_bf = (u16*)ws;                     // 51,380,224 B
  u16*   t_bf  = (u16*)(ws + 51380224);        // 12,845,056 B
  u16*   WfT   = (u16*)(ws + 64225280);        //  2,097,152 B
  u16*   WaT   = (u16*)(ws + 66322432);        //  2,097,152 B
  float* hsbuf = (float*)(ws + 68419584);      //    131,072 B

  cvt_bf16_kernel<<<4096, 256, 0, stream>>>(fv, fv_bf, (B_*L_*D_)/4);
  transpose_cvt_kernel<<<dim3(I_/32, D_/32), dim3(32,8), 0, stream>>>(W_f, WfT, D_, I_);
  transpose_cvt_kernel<<<dim3(D_/32, I_/32), dim3(32,8), 0, stream>>>(W_a, WaT, I_, D_);
  hs_kernel<<<dim3(I_/256, B_), 256, 0, stream>>>(hidden, W_h, b_h, hsbuf);

  gemm1_kernel<<<dim3(I_/128, M_/64), 256, 0, stream>>>(fv_bf, WfT, b_f, hsbuf, t_bf);
  gemm2_fused_kernel<<<dim3(D_/128, B_), 256, 0, stream>>>(t_bf, WaT, b_a, fv, out);
}

// Round 5
// 330.403 us; speedup vs baseline: 1.2401x; 1.0857x over previous
//
#include <hip/hip_runtime.h>

#define B_ 64
#define L_ 196
#define D_ 2048
#define I_ 512
#define M_ (B_*L_)   // 12544

typedef __attribute__((ext_vector_type(8))) short bf16x8;
typedef __attribute__((ext_vector_type(4))) float f32x4;
typedef unsigned short u16;

__device__ __forceinline__ u16 f2bf(float x){
  unsigned u = __float_as_uint(x);
  u += 0x7fffu + ((u >> 16) & 1u);
  return (u16)(u >> 16);
}

__device__ __forceinline__ void gld16(const void* g, void* l){
  __builtin_amdgcn_global_load_lds(
      (const __attribute__((address_space(1))) void*)g,
      (__attribute__((address_space(3))) void*)l, 16, 0, 0);
}

// gfx9 waitcnt imm: vmcnt[3:0]=bits3:0, expcnt=bits6:4, lgkmcnt=bits11:8, vmcnt[5:4]=bits15:14
template<int N> __device__ __forceinline__ void wait_vm(){
  __builtin_amdgcn_s_waitcnt((N&15) | ((N&48)<<10) | (7<<4) | (15<<8));
}
__device__ __forceinline__ void wait_lgkm0(){
  __builtin_amdgcn_s_waitcnt(15 | (48<<10) | (7<<4));   // vmcnt=63 (no wait), lgkmcnt=0
}
__device__ __forceinline__ void bar(){
  asm volatile("" ::: "memory");
  __builtin_amdgcn_s_barrier();
  asm volatile("" ::: "memory");
}

// fp32 -> bf16, n4 = count/4
__global__ void cvt_bf16_kernel(const float* __restrict__ in, u16* __restrict__ out, int n4){
  int i = blockIdx.x*blockDim.x + threadIdx.x;
  int stride = gridDim.x*blockDim.x;
  for (; i < n4; i += stride){
    float4 v = ((const float4*)in)[i];
    ushort4 o;
    o.x = f2bf(v.x); o.y = f2bf(v.y); o.z = f2bf(v.z); o.w = f2bf(v.w);
    ((ushort4*)out)[i] = o;
  }
}

// in: [R,C] fp32 row-major  ->  out: [C,R] bf16 row-major
__global__ void transpose_cvt_kernel(const float* __restrict__ in, u16* __restrict__ out, int R, int C){
  __shared__ float tile[32][33];
  int c0 = blockIdx.x*32, r0 = blockIdx.y*32;
  int tx = threadIdx.x, ty = threadIdx.y; // blockDim (32,8)
  for (int i=0;i<32;i+=8)
    tile[ty+i][tx] = in[(size_t)(r0+ty+i)*C + c0 + tx];
  __syncthreads();
  for (int i=0;i<32;i+=8)
    out[(size_t)(c0+ty+i)*R + r0 + tx] = f2bf(tile[tx][ty+i]);
}

// hs[b][n] = b_h[n] + sum_k hidden[b][k]*W_h[k][n].  k-split over 4 groups of 128,
// grid (I_/64, B_) = 512 blocks (2/CU) — 4x shorter serial chain than R4's 128-block version.
__launch_bounds__(256)
__global__ void hs_kernel(const float* __restrict__ hidden, const float* __restrict__ Wh,
                          const float* __restrict__ bh, float* __restrict__ hs){
  __shared__ float red[4][64];
  const int nl = threadIdx.x & 63, kg = threadIdx.x >> 6;
  const int n = blockIdx.x*64 + nl, b = blockIdx.y;
  const float* hrow = hidden + b*I_;
  float a0=0.f, a1=0.f;
  #pragma unroll
  for (int k=kg*128; k<kg*128+128; k+=2){
    a0 = fmaf(hrow[k+0], Wh[(size_t)(k+0)*I_ + n], a0);
    a1 = fmaf(hrow[k+1], Wh[(size_t)(k+1)*I_ + n], a1);
  }
  red[kg][nl] = a0 + a1;
  __syncthreads();
  if (kg == 0)
    hs[b*I_ + n] = bh[n] + (red[0][nl]+red[1][nl]) + (red[2][nl]+red[3][nl]);
}

// GEMM1: t = bf16(fv_bf @ WfT^T + b_f + hs[batch])   [M,512]
// BM=64, BN=128, BK=64, double-buffered LDS, fine-grained vmcnt (never drains in-flight prefetch).
__launch_bounds__(256)
__global__ void gemm1_kernel(const u16* __restrict__ A, const u16* __restrict__ Bt,
                             const float* __restrict__ bias, const float* __restrict__ hs,
                             u16* __restrict__ outb)
{
  constexpr int K = D_, BK = 64, NIT = K/BK;     // 32
  __shared__ __align__(16) u16 Als[2][64*64];    // 8 KB each
  __shared__ __align__(16) u16 Bls[2][128*64];   // 16 KB each

  const int tid = threadIdx.x, lane = tid&63, wave = tid>>6;
  const int m0 = blockIdx.y*64, n0 = blockIdx.x*128;
  const int q = lane>>4, mr = lane&15;
  const int wrow = (wave&1)*32, wcol = (wave>>1)*64;
  const int lrow = lane>>3, kc = (lane&7)^lrow;  // XOR swizzle (0 conflicts, R3)

  const u16* Ag[2]; int Alo[2];
  #pragma unroll
  for (int u=0;u<2;++u){ int j = wave*2+u; Ag[u] = A + (size_t)(m0 + j*8 + lrow)*K + kc*8; Alo[u] = j*512; }
  const u16* Bg[4]; int Blo[4];
  #pragma unroll
  for (int u=0;u<4;++u){ int j = wave*4+u; Bg[u] = Bt + (size_t)(n0 + j*8 + lrow)*K + kc*8; Blo[u] = j*512; }

  int aoff[2][2], boff[4][2];
  #pragma unroll
  for (int i=0;i<2;i++)
    #pragma unroll
    for (int s=0;s<2;s++){ int R = wrow + i*16 + mr; aoff[i][s] = R*64 + (((s*4+q) ^ (mr&7))*8); }
  #pragma unroll
  for (int j=0;j<4;j++)
    #pragma unroll
    for (int s=0;s<2;s++){ int C = wcol + j*16 + mr; boff[j][s] = C*64 + (((s*4+q) ^ (mr&7))*8); }

  f32x4 acc[2][4];
  #pragma unroll
  for (int i=0;i<2;i++)
    #pragma unroll
    for (int j=0;j<4;j++) acc[i][j] = (f32x4){0.f,0.f,0.f,0.f};

  #pragma unroll
  for (int u=0;u<2;++u) gld16(Ag[u],    &Als[0][Alo[u]]);
  #pragma unroll
  for (int u=0;u<4;++u) gld16(Bg[u],    &Bls[0][Blo[u]]);
  #pragma unroll
  for (int u=0;u<2;++u) gld16(Ag[u]+BK, &Als[1][Alo[u]]);
  #pragma unroll
  for (int u=0;u<4;++u) gld16(Bg[u]+BK, &Bls[1][Blo[u]]);

  for (int i=0;i<NIT;++i){
    if (i+1<NIT) wait_vm<6>(); else wait_vm<0>();  // drain ONLY tile i
    bar();
    const u16* Ab = Als[i&1];
    const u16* Bb = Bls[i&1];
    bf16x8 af[2][2], bg[4][2];
    #pragma unroll
    for (int s=0;s<2;s++){
      #pragma unroll
      for (int i2=0;i2<2;i2++) af[i2][s] = *(const bf16x8*)(Ab + aoff[i2][s]);
      #pragma unroll
      for (int j=0;j<4;j++)    bg[j][s]  = *(const bf16x8*)(Bb + boff[j][s]);
    }
    wait_lgkm0();      // frags in regs
    bar();             // buf[i&1] free
    if (i+2<NIT){
      int k0 = (i+2)*BK;
      #pragma unroll
      for (int u=0;u<2;++u) gld16(Ag[u]+k0, &Als[i&1][Alo[u]]);
      #pragma unroll
      for (int u=0;u<4;++u) gld16(Bg[u]+k0, &Bls[i&1][Blo[u]]);
    }
    #pragma unroll
    for (int s=0;s<2;s++)
      #pragma unroll
      for (int i2=0;i2<2;i2++)
        #pragma unroll
        for (int j=0;j<4;j++)
          acc[i2][j] = __builtin_amdgcn_mfma_f32_16x16x32_bf16(af[i2][s], bg[j][s], acc[i2][j], 0,0,0);
  }

  #pragma unroll
  for (int i2=0;i2<2;i2++){
    #pragma unroll
    for (int j=0;j<4;j++){
      int gcol = n0 + wcol + j*16 + mr;
      float bcol = bias[gcol];
      #pragma unroll
      for (int r=0;r<4;r++){
        int grow = m0 + wrow + i2*16 + q*4 + r;
        int batch = grow / L_;
        outb[(size_t)grow*I_ + gcol] = f2bf(acc[i2][j][r] + bcol + hs[batch*I_ + gcol]);
      }
    }
  }
}

// Fused GEMM2 + softmax + z.  BN=64: block = (batch b, 64 e-cols), each wave owns 16 cols.
// acc[13] (52 VGPR) instead of R4's acc[13][2] (104) — occupancy was 10% at VGPR=184/LDS=48K.
// LDS 40 KB -> 4 blocks/CU; grid (32,64)=2048 blocks.  5 loads/wave/iter (4 A + 1 B).
__launch_bounds__(256)
__global__ void gemm2_fused_kernel(const u16* __restrict__ T, const u16* __restrict__ Wa,
                                   const float* __restrict__ b_a, const float* __restrict__ fv,
                                   float* __restrict__ out)
{
  constexpr int K = I_, BK = 32, NIT = K/BK;     // 16
  __shared__ __align__(16) u16 Als[2][256*32];   // 16 KB each (rows 196..255 staged, masked)
  __shared__ __align__(16) u16 Bls[2][64*32];    // 4 KB each

  const int tid = threadIdx.x, lane = tid&63, wave = tid>>6;
  const int b = blockIdx.y, n0 = blockIdx.x*64;
  const int q = lane>>4, mr = lane&15;
  const int l16 = lane>>2, kc4 = (lane&3)^(l16&3);

  // A: 16 issues of 16 rows x 32 k; wave takes 4
  const u16* Ag[4]; int Alo[4];
  #pragma unroll
  for (int u=0;u<4;++u){
    int j = wave*4+u;
    int grow = b*L_ + j*16 + l16; if (grow > M_-1) grow = M_-1;   // clamp (masked later)
    Ag[u] = T + (size_t)grow*K + kc4*8; Alo[u] = j*512;
  }
  // B: 4 issues; wave takes 1
  const u16* Bg = Wa + (size_t)(n0 + wave*16 + l16)*K + kc4*8;
  const int  Blo = wave*512;

  const int abase = mr*32 + ((q ^ (mr&3))*8);    // + i*512 per frag
  const int col  = n0 + wave*16 + mr;            // this lane's e-column
  const int boff = col - n0 == (wave*16+mr) ? ((wave*16+mr)*32 + ((q ^ (mr&3))*8)) : 0; // = C*32+...

  f32x4 acc[13];
  #pragma unroll
  for (int i=0;i<13;i++) acc[i] = (f32x4){0,0,0,0};

  // preload tiles 0,1 (10 outstanding per wave)
  #pragma unroll
  for (int u=0;u<4;++u) gld16(Ag[u],    &Als[0][Alo[u]]);
  gld16(Bg,    &Bls[0][Blo]);
  #pragma unroll
  for (int u=0;u<4;++u) gld16(Ag[u]+BK, &Als[1][Alo[u]]);
  gld16(Bg+BK, &Bls[1][Blo]);

  for (int it=0; it<NIT; ++it){
    if (it+1<NIT) wait_vm<5>(); else wait_vm<0>();
    bar();
    const u16* Ab = Als[it&1];
    const u16* Bb = Bls[it&1];
    bf16x8 bg0 = *(const bf16x8*)(Bb + boff);
    bf16x8 af[13];
    #pragma unroll
    for (int i=0;i<13;++i) af[i] = *(const bf16x8*)(Ab + abase + i*512);
    wait_lgkm0();
    bar();
    if (it+2<NIT){
      int k0 = (it+2)*BK;
      #pragma unroll
      for (int u=0;u<4;++u) gld16(Ag[u]+k0, &Als[it&1][Alo[u]]);
      gld16(Bg+k0, &Bls[it&1][Blo]);
    }
    #pragma unroll
    for (int i=0;i<13;++i)
      acc[i] = __builtin_amdgcn_mfma_f32_16x16x32_bf16(af[i], bg0, acc[i], 0,0,0);
  }

  // ---- fused epilogue: e = acc + b_a; softmax over 196 rows; alpha + z ----
  const bool v12 = (q == 0);                     // frag 12: rows 192..195 valid only for q==0
  float bc = b_a[col];
  #pragma unroll
  for (int i=0;i<13;++i)
    #pragma unroll
    for (int r=0;r<4;++r) acc[i][r] += bc;

  float m = -3.4e38f;
  #pragma unroll
  for (int i=0;i<12;++i)
    #pragma unroll
    for (int r=0;r<4;++r) m = fmaxf(m, acc[i][r]);
  if (v12)
    #pragma unroll
    for (int r=0;r<4;++r) m = fmaxf(m, acc[12][r]);
  m = fmaxf(m, __shfl_xor(m, 16));
  m = fmaxf(m, __shfl_xor(m, 32));

  float s = 0.f;
  #pragma unroll
  for (int i=0;i<12;++i)
    #pragma unroll
    for (int r=0;r<4;++r){ float e = __expf(acc[i][r]-m); acc[i][r] = e; s += e; }
  if (v12)
    #pragma unroll
    for (int r=0;r<4;++r){ float e = __expf(acc[12][r]-m); acc[12][r] = e; s += e; }
  s += __shfl_xor(s, 16);
  s += __shfl_xor(s, 32);
  float inv = 1.f/s;

  float* alpha = out + (size_t)B_*D_ + (size_t)b*L_*D_;
  const float* fvb = fv + (size_t)b*L_*D_;
  float z = 0.f;
  #pragma unroll
  for (int i=0;i<13;++i){
    if (i < 12 || v12){
      #pragma unroll
      for (int r=0;r<4;++r){
        int row = i*16 + q*4 + r;               // < 196 when valid
        float a = acc[i][r] * inv;
        alpha[(size_t)row*D_ + col] = a;
        z = fmaf(a, fvb[(size_t)row*D_ + col], z);
      }
    }
  }
  z += __shfl_xor(z, 16);
  z += __shfl_xor(z, 32);
  if (q == 0) out[(size_t)b*D_ + col] = z;
}

extern "C" void kernel_launch(void* const* d_in, const int* in_sizes, int n_in,
                              void* d_out, int out_size, void* d_ws, size_t ws_size,
                              hipStream_t stream){
  (void)in_sizes; (void)n_in; (void)out_size; (void)ws_size;
  const float* fv     = (const float*)d_in[0];
  const float* hidden = (const float*)d_in[1];
  const float* W_f    = (const float*)d_in[2];
  const float* b_f    = (const float*)d_in[3];
  const float* W_h    = (const float*)d_in[4];
  const float* b_h    = (const float*)d_in[5];
  const float* W_a    = (const float*)d_in[6];
  const float* b_a    = (const float*)d_in[7];
  float* out = (float*)d_out;

  char* ws = (char*)d_ws;
  u16*   fv_bf = (u16*)ws;                     // 51,380,224 B
  u16*   t_bf  = (u16*)(ws + 51380224);        // 12,845,056 B
  u16*   WfT   = (u16*)(ws + 64225280);        //  2,097,152 B
  u16*   WaT   = (u16*)(ws + 66322432);        //  2,097,152 B
  float* hsbuf = (float*)(ws + 68419584);      //    131,072 B

  cvt_bf16_kernel<<<4096, 256, 0, stream>>>(fv, fv_bf, (B_*L_*D_)/4);
  transpose_cvt_kernel<<<dim3(I_/32, D_/32), dim3(32,8), 0, stream>>>(W_f, WfT, D_, I_);
  transpose_cvt_kernel<<<dim3(D_/32, I_/32), dim3(32,8), 0, stream>>>(W_a, WaT, I_, D_);
  hs_kernel<<<dim3(I_/64, B_), 256, 0, stream>>>(hidden, W_h, b_h, hsbuf);

  gemm1_kernel<<<dim3(I_/128, M_/64), 256, 0, stream>>>(fv_bf, WfT, b_f, hsbuf, t_bf);
  gemm2_fused_kernel<<<dim3(D_/64, B_), 256, 0, stream>>>(t_bf, WaT, b_a, fv, out);
}